// Round 17
// baseline (3915.750 us; speedup 1.0000x reference)
//
#include <hip/hip_runtime.h>
#include <hip/hip_bf16.h>
#include <math.h>

#define DEVI __device__ __forceinline__

// ---------------- coords copy + input 1x1 conv (C=3 -> O=8) + stats zero
__global__ void k_feat0(const float* __restrict__ x,
                        const float* __restrict__ w_in,
                        const float* __restrict__ b_in,
                        float* __restrict__ coords0, float* __restrict__ feat0,
                        float* __restrict__ stats)
{
  int t = blockIdx.x*blockDim.x + threadIdx.x;   // (b,n) flat
  if (t < 384) stats[t] = 0.f;                   // fused k_zero
  if (t >= 8*4096) return;
  float cx = x[t*3+0], cy = x[t*3+1], cz = x[t*3+2];
  coords0[t*3+0]=cx; coords0[t*3+1]=cy; coords0[t*3+2]=cz;
  #pragma unroll
  for (int o=0;o<8;o++){
    float s = __fadd_rn(__fadd_rn(__fmul_rn(cx,w_in[o*3+0]),
                                  __fmul_rn(cy,w_in[o*3+1])),
                        __fmul_rn(cz,w_in[o*3+2]));
    feat0[t*8+o] = __fadd_rn(s, b_in[o]);
  }
}

// ---------------------------------------------------------------- FPS
// 4 waves/batch (256 thr), P=16/8/2 coords+dist in regs (~65 VGPR state).
// LDS ~90KB -> 1 block/CU -> allocator budget 256 VGPR (verified model):
// no spill. Inner loop uses fmaf (R2==R3 margin evidence: selections robust
// to >>1ulp distance perturbation). Reduction carries monotone u64 key
// (f32bits(d)<<32)|~idx — max == max d, tie -> min idx (verified argmax).
// Cross-wave: lane63 writes 1 u64, ONE barrier, scan 4 keys; center coords
// from LDS point copy (broadcast). No per-iter global writes.
template<int CTRL>
DEVI void dppmax64(unsigned& hi, unsigned& lo){
  unsigned oh = (unsigned)__builtin_amdgcn_update_dpp((int)hi,(int)hi,CTRL,0xF,0xF,false);
  unsigned ol = (unsigned)__builtin_amdgcn_update_dpp((int)lo,(int)lo,CTRL,0xF,0xF,false);
  bool tk = (oh > hi) || (oh == hi && ol > lo);
  hi = tk?oh:hi; lo = tk?ol:lo;
}

template<int P>
DEVI void fps_stage(float (&px)[P], float (&py)[P], float (&pz)[P],
                    const float* cpx, const float* cpy, const float* cpz,
                    int m, unsigned long long (*red)[4], int* ssel,
                    float* snx, float* sny, float* snz, int tid)
{
  const int wv = tid>>6, lane = tid&63;
  float dist[P];
  #pragma unroll
  for (int p=0;p<P;p++) dist[p]=1e10f;
  float sx=cpx[0], sy=cpy[0], sz=cpz[0];
  if (tid==0){
    ssel[0]=0;
    if (snx){ snx[0]=sx; sny[0]=sy; snz[0]=sz; }
  }
  for (int it=1; it<m; it++){
    float bv=-3.4e38f; int bidx=0;
    #pragma unroll
    for (int p=0;p<P;p++){
      float dx=__fsub_rn(px[p],sx);
      float dy=__fsub_rn(py[p],sy);
      float dz=__fsub_rn(pz[p],sz);
      float d = fmaf(dz,dz, fmaf(dy,dy, __fmul_rn(dx,dx)));
      d = fminf(dist[p], d);
      dist[p] = d;
      if (d > bv){ bv=d; bidx=tid+(p<<8); }   // ascending idx: first wins
    }
    unsigned hi = (unsigned)__float_as_int(bv);  // d>=0: order-preserving
    unsigned lo = ~(unsigned)bidx;
    dppmax64<0x111>(hi,lo);   // row_shr:1
    dppmax64<0x112>(hi,lo);   // row_shr:2
    dppmax64<0x114>(hi,lo);   // row_shr:4
    dppmax64<0x118>(hi,lo);   // row_shr:8
    dppmax64<0x142>(hi,lo);   // row_bcast15
    dppmax64<0x143>(hi,lo);   // row_bcast31 -> lane63 = wave winner
    const int buf = it & 1;   // double buffer -> 1 barrier/iter safe
    if (lane==63) red[buf][wv] = ((unsigned long long)hi<<32) | lo;
    __syncthreads();
    unsigned long long best = red[buf][0];
    #pragma unroll
    for (int w=1;w<4;w++){
      unsigned long long o = red[buf][w];
      if (o > best) best = o;
    }
    int gi = (int)(~(unsigned)(best & 0xffffffffULL));
    sx = cpx[gi]; sy = cpy[gi]; sz = cpz[gi];   // LDS broadcast reads
    if (tid==0){                                // LDS-only per-iter writes
      ssel[it]=gi;
      if (snx){ snx[it]=sx; sny[it]=sy; snz[it]=sz; }
    }
  }
}

// ----------------------------------------- KNN wave body (one wave = one q)
DEVI void knn_one(const float* __restrict__ cq, int Nq,
                  const float* __restrict__ ck, int Nk,
                  int* __restrict__ idx_out, int b, int q, int lane)
{
  size_t r3 = ((size_t)b*Nq+q)*3;
  float qx=cq[r3], qy=cq[r3+1], qz=cq[r3+2];
  float sqq = __fadd_rn(__fadd_rn(__fmul_rn(qx,qx),__fmul_rn(qy,qy)),
                        __fmul_rn(qz,qz));
  float bd[16]; int bi[16];
  #pragma unroll
  for (int s=0;s<16;s++){ bd[s]=3.4e38f; bi[s]=0x7ffffff0+s; }
  float wv = 3.4e38f; int wslot = 15;
  const float* ckb = ck + (size_t)b*Nk*3;
  for (int j=lane; j<Nk; j+=64){
    float kx=ckb[3*j], ky=ckb[3*j+1], kz=ckb[3*j+2];
    float sk  = __fadd_rn(__fadd_rn(__fmul_rn(kx,kx),__fmul_rn(ky,ky)),
                          __fmul_rn(kz,kz));
    float dot = __fadd_rn(__fadd_rn(__fmul_rn(qx,kx),__fmul_rn(qy,ky)),
                          __fmul_rn(qz,kz));
    float d   = __fadd_rn(__fsub_rn(sqq, __fmul_rn(2.0f,dot)), sk);
    if (d < wv){
      #pragma unroll
      for (int s=0;s<16;s++) if (s==wslot){ bd[s]=d; bi[s]=j; }
      wv=bd[0]; int wvi=bi[0]; wslot=0;
      #pragma unroll
      for (int s=1;s<16;s++)
        if (bd[s]>wv || (bd[s]==wv && bi[s]>wvi)){ wv=bd[s]; wvi=bi[s]; wslot=s; }
    }
  }
  // wave merge: extract global 16 smallest (d, then idx)
  unsigned mask = 0;
  float mv = __int_as_float(0x7f800000); int mi = 0x7fffffff, ms = 0;
  #pragma unroll
  for (int s=0;s<16;s++)
    if (bd[s]<mv || (bd[s]==mv && bi[s]<mi)){ mv=bd[s]; mi=bi[s]; ms=s; }
  int myout = 0;
  #pragma unroll
  for (int r=0;r<16;r++){
    float gv = mv; int gi = mi;
    #pragma unroll
    for (int off=1; off<64; off<<=1){
      float ov = __shfl_xor(gv, off);
      int   oi = __shfl_xor(gi, off);
      if (ov<gv || (ov==gv && oi<gi)){ gv=ov; gi=oi; }
    }
    if (lane == r) myout = gi;
    if (mv==gv && mi==gi){
      mask |= 1u<<ms;
      mv = __int_as_float(0x7f800000); mi = 0x7fffffff; ms = 0;
      #pragma unroll
      for (int s=0;s<16;s++){
        bool ok = ((mask>>s)&1u)==0u;
        if (ok && (bd[s]<mv || (bd[s]==mv && bi[s]<mi))){ mv=bd[s]; mi=bi[s]; ms=s; }
      }
    }
  }
  if (lane<16) idx_out[((size_t)b*Nq+q)*16 + lane] = myout;
}

// --------------------------------------------------- GEMM block body
#define GEMM_M 8
DEVI void gemm_block(const float* __restrict__ feat, int Nk, int C, int O,
                     const float* __restrict__ wlT, const float* __restrict__ wqT,
                     float* __restrict__ yk, float* __restrict__ yq,
                     int b, int rowblk, float* sf, int tid)
{
  const int o = tid & (O-1);
  const int rg = tid / O;
  const int R = 256 / O;
  const int rowsPB = R*GEMM_M;
  const int row0 = rowblk * rowsPB;
  const int Cp = C+1;
  const float* src = feat + ((size_t)b*Nk + row0)*C;
  for (int i=tid; i<rowsPB*C; i+=256){
    int r = i / C, c = i - r*C;
    sf[r*Cp + c] = src[i];
  }
  __syncthreads();
  float ak[GEMM_M], aq[GEMM_M];
  #pragma unroll
  for (int m=0;m<GEMM_M;m++){ ak[m]=0.f; aq[m]=0.f; }
  const float* lp = wlT + o;
  const float* qp = wqT + o;
  const float* sfr = sf + rg*GEMM_M*Cp;
  for (int c=0;c<C;c++){
    float wl = lp[(size_t)c*O];
    float wq = qp[(size_t)c*O];
    #pragma unroll
    for (int m=0;m<GEMM_M;m++){
      float xv = sfr[m*Cp + c];
      ak[m] = fmaf(xv, wl, ak[m]);
      aq[m] = fmaf(xv, wq, aq[m]);
    }
  }
  size_t obase = ((size_t)b*Nk + row0 + rg*GEMM_M)*O + o;
  #pragma unroll
  for (int m=0;m<GEMM_M;m++){
    yk[obase + (size_t)m*O] = ak[m];
    yq[obase + (size_t)m*O] = aq[m];
  }
}

__global__ void k_gemm_dual(const float* __restrict__ feat, int Nk, int C, int O,
                            const float* __restrict__ wlT, const float* __restrict__ wqT,
                            float* __restrict__ yk, float* __restrict__ yq)
{
  extern __shared__ float sf[];
  gemm_block(feat, Nk, C, O, wlT, wqT, yk, yq, blockIdx.y, blockIdx.x,
             sf, threadIdx.x);
}

// ---- fused: FPS (blocks 0..7) + layer-1 KNN + layer-1 GEMM (independent)
__global__ __launch_bounds__(256) void k_fps_knn1(
    const float* __restrict__ coords0,
    int* __restrict__ idx1, int* __restrict__ idx2, int* __restrict__ idx3,
    float* __restrict__ c1, float* __restrict__ c2, float* __restrict__ c3,
    float* __restrict__ out, int* __restrict__ knn1,
    const float* __restrict__ f0, const float* __restrict__ wl1,
    const float* __restrict__ wq1, float* __restrict__ yk, float* __restrict__ yq)
{
  __shared__ float s1x[4096], s1y[4096], s1z[4096];  // 48 KB stage-1 copy
  __shared__ float s2x[2048], s2y[2048], s2z[2048];  // 24 KB staging
  __shared__ float s3x[512],  s3y[512],  s3z[512];   //  6 KB
  __shared__ float s4x[128],  s4y[128],  s4z[128];   //  1.5 KB
  __shared__ int   ssel[2048];                       //  8 KB
  __shared__ unsigned long long red[2][4];           //  cross-wave merge
  const int tid = threadIdx.x;
  if (blockIdx.x >= 8){
    int flat = blockIdx.x - 8;
    if (flat < 8*1024){                              // layer-1 KNN, 4 q/block
      int b = flat >> 10, qb = flat & 1023;
      int q = qb*4 + (tid>>6);
      knn_one(coords0, 4096, coords0, 4096, knn1, b, q, tid&63);
    } else {                                         // layer-1 GEMM
      int g = flat - 8*1024;
      int b = g >> 6, rowblk = g & 63;               // 64 row-blocks (Nk=4096)
      gemm_block(f0, 4096, 8, 32, wl1, wq1, yk, yq, b, rowblk, s1x, tid);
    }
    return;
  }
  const int b = blockIdx.x;
  const float* cb = coords0 + (size_t)b*4096*3;
  { // stage 1: 4096 -> 2048   (P=16, j = tid + p*256)
    float px[16], py[16], pz[16];
    #pragma unroll
    for (int p=0;p<16;p++){
      int j = tid + (p<<8);
      float X=cb[3*j], Y=cb[3*j+1], Z=cb[3*j+2];
      px[p]=X; py[p]=Y; pz[p]=Z;
      s1x[j]=X; s1y[j]=Y; s1z[j]=Z;
    }
    __syncthreads();
    fps_stage<16>(px,py,pz, s1x,s1y,s1z, 2048, red, ssel, s2x,s2y,s2z, tid);
  }
  __syncthreads();
  { // flush stage 1
    float* c1b = c1 + (size_t)b*2048*3;
    for (int i=tid;i<2048;i+=256){
      idx1[b*2048+i]=ssel[i];
      c1b[3*i]=s2x[i]; c1b[3*i+1]=s2y[i]; c1b[3*i+2]=s2z[i];
    }
  }
  { // stage 2: 2048 -> 512    (P=8)
    float px[8], py[8], pz[8];
    #pragma unroll
    for (int p=0;p<8;p++){
      int j = tid + (p<<8);
      px[p]=s2x[j]; py[p]=s2y[j]; pz[p]=s2z[j];
    }
    __syncthreads();                 // protect ssel rewrite vs flush reads
    fps_stage<8>(px,py,pz, s2x,s2y,s2z, 512, red, ssel, s3x,s3y,s3z, tid);
  }
  __syncthreads();
  {
    float* c2b = c2 + (size_t)b*512*3;
    for (int i=tid;i<512;i+=256){
      idx2[b*512+i]=ssel[i];
      c2b[3*i]=s3x[i]; c2b[3*i+1]=s3y[i]; c2b[3*i+2]=s3z[i];
    }
  }
  { // stage 3: 512 -> 128     (P=2)
    float px[2], py[2], pz[2];
    #pragma unroll
    for (int p=0;p<2;p++){
      int j = tid + (p<<8);
      px[p]=s3x[j]; py[p]=s3y[j]; pz[p]=s3z[j];
    }
    __syncthreads();
    fps_stage<2>(px,py,pz, s3x,s3y,s3z, 128, red, ssel, s4x,s4y,s4z, tid);
  }
  __syncthreads();
  {
    float* c3b = c3 + (size_t)b*128*3;
    float* ob  = out + (size_t)b*128*3;
    for (int i=tid;i<128;i+=256){
      idx3[b*128+i]=ssel[i];
      float X=s4x[i],Y=s4y[i],Z=s4z[i];
      c3b[3*i]=X; c3b[3*i+1]=Y; c3b[3*i+2]=Z;
      ob[3*i]=X; ob[3*i+1]=Y; ob[3*i+2]=Z;
    }
  }
}

// ----------------------- weight split+transpose, all 6 layers in one launch
struct WtParams {
  const float* W[6];
  float* wl[6];
  float* wq[6];
  int O[6], C[6], OC[6];
};
__global__ void k_wt_all(WtParams p){
  int s = blockIdx.y;
  int t = blockIdx.x*blockDim.x + threadIdx.x;
  int OC = p.OC[s];
  if (t >= OC) return;
  int C = p.C[s], O = p.O[s];
  int o = t / C, c = t - o*C;
  const float* W = p.W[s];
  float wlv = W[o*2*C + c];
  float wrv = W[o*2*C + C + c];
  p.wl[s][c*O+o] = wlv;
  p.wq[s][c*O+o] = wrv - wlv;
}

// ---------------------------------- gather neighbors + max_k + GN statistics
__global__ void k_gather(const float* __restrict__ yk, const float* __restrict__ yq,
                         const int* __restrict__ knnidx, const int* __restrict__ qmap,
                         int Nq, int Nk, int O,
                         float* __restrict__ vmax, float* __restrict__ stats)
{
  const int b = blockIdx.y;
  const int o = threadIdx.x & (O-1);
  const int rg = threadIdx.x / O;
  const int R = blockDim.x / O;
  float ls=0.f, ls2=0.f;
  const float* ykb = yk + (size_t)b*Nk*O;
  const float* yqb = yq + (size_t)b*Nk*O;
  for (int nq = blockIdx.x*R + rg; nq < Nq; nq += gridDim.x*R){
    int qj = qmap ? qmap[b*Nq+nq] : nq;
    float vq = yqb[(size_t)qj*O + o];
    const int* ip = knnidx + ((size_t)b*Nq+nq)*16;
    float vmx = -3.4e38f;
    #pragma unroll
    for (int k=0;k<16;k++){
      int j = ip[k];
      float v = ykb[(size_t)j*O+o] + vq;
      vmx = fmaxf(vmx, v);
      ls += v; ls2 = fmaf(v,v,ls2);
    }
    vmax[((size_t)b*Nq+nq)*O+o] = vmx;
  }
  int span = O/4; if (span>64) span=64;          // group-aligned lane segments
  for (int mm=1; mm<span; mm<<=1){
    ls  += __shfl_xor(ls, mm);
    ls2 += __shfl_xor(ls2, mm);
  }
  __shared__ float sred[8];
  if (threadIdx.x<8) sred[threadIdx.x]=0.f;
  __syncthreads();
  int lane = threadIdx.x & 63;
  if ((lane & (span-1))==0){
    int g = (o*4)/O;
    atomicAdd(&sred[g*2+0], ls);
    atomicAdd(&sred[g*2+1], ls2);
  }
  __syncthreads();
  if (threadIdx.x<8) atomicAdd(&stats[b*8+threadIdx.x], sred[threadIdx.x]);
}

// ------------------- GN normalize + leaky (norm body, used by two kernels)
DEVI void norm_body(const float* __restrict__ vmax, const float* __restrict__ stats,
                    const float* __restrict__ gamma, const float* __restrict__ beta,
                    int Nq, int O, float invcnt, float* __restrict__ outf,
                    int b, int blk, int tid)
{
  const int n = Nq*O;
  int i = blk*256 + tid;
  if (i >= n) return;
  int o = i & (O-1);
  int g = (o*4)/O;
  float s1 = stats[b*8+g*2], s2 = stats[b*8+g*2+1];
  float mu = s1*invcnt;
  float var = fmaf(-mu,mu, s2*invcnt);
  float rs = 1.0f/sqrtf(var+1e-5f);
  float v = (vmax[(size_t)b*n + i]-mu)*rs*gamma[o] + beta[o];
  outf[(size_t)b*n + i] = (v>=0.f)? v : 0.2f*v;
}

__global__ void k_norm(const float* __restrict__ vmax, const float* __restrict__ stats,
                       const float* __restrict__ gamma, const float* __restrict__ beta,
                       int Nq, int O, float invcnt, float* __restrict__ outf)
{
  norm_body(vmax, stats, gamma, beta, Nq, O, invcnt, outf,
            blockIdx.y, blockIdx.x, threadIdx.x);
}

// ------------- fused: norm for layer s  +  KNN for layer s+1 (independent)
__global__ void k_norm_knn(const float* __restrict__ vmax, const float* __restrict__ stats,
                           const float* __restrict__ gamma, const float* __restrict__ beta,
                           int Nqn, int O, float invcnt, float* __restrict__ outf,
                           int nb,
                           const float* __restrict__ cq, int Nq2,
                           const float* __restrict__ ck, int Nk2,
                           int* __restrict__ knn_out)
{
  const int b = blockIdx.y;
  if ((int)blockIdx.x < nb){
    norm_body(vmax, stats, gamma, beta, Nqn, O, invcnt, outf,
              b, blockIdx.x, threadIdx.x);
  } else {
    int qb = blockIdx.x - nb;
    int q = qb*4 + (threadIdx.x>>6);
    if (q < Nq2) knn_one(cq, Nq2, ck, Nk2, knn_out, b, q, threadIdx.x&63);
  }
}

// ===========================================================================
extern "C" void kernel_launch(void* const* d_in, const int* in_sizes, int n_in,
                              void* d_out, int out_size, void* d_ws, size_t ws_size,
                              hipStream_t stream)
{
  const int B = 8;
  const float* x    = (const float*)d_in[0];
  const float* w_in = (const float*)d_in[4];
  const float* b_in = (const float*)d_in[5];
  const float *Wm[6], *Gm[6], *Bm[6];
  for (int i=0;i<6;i++){
    Wm[i]=(const float*)d_in[6+3*i];
    Gm[i]=(const float*)d_in[6+3*i+1];
    Bm[i]=(const float*)d_in[6+3*i+2];
  }
  float* ws = (float*)d_ws;
  float* out = (float*)d_out;
  const size_t OFF_C0=0,        OFF_F0=98304,   OFF_F1=360448,  OFF_F2=1409024,
               OFF_F4=2457600,  OFF_F5=2981888, OFF_F6=3506176, OFF_F7=3768320,
               OFF_C1=4030464,  OFF_C2=4079616, OFF_C3=4091904,
               OFF_YK=4094976,  OFF_YQ=6192128, OFF_VM=8289280,
               OFF_WL=9337856,  OFF_WQ=9468928, OFF_ST=9600000,
               OFF_I1=9600384,  OFF_I2=9616768, OFF_I3=9620864, OFF_KNN=9621888,
               TOTAL=10146176;  // ~40.6 MB
  if (ws_size < TOTAL*sizeof(float)) return;
  float *c0=ws+OFF_C0, *f0=ws+OFF_F0, *f1=ws+OFF_F1, *f2=ws+OFF_F2,
        *f4=ws+OFF_F4, *f5=ws+OFF_F5, *f6=ws+OFF_F6,
        *c1=ws+OFF_C1, *c2=ws+OFF_C2, *c3=ws+OFF_C3,
        *yk=ws+OFF_YK, *yq=ws+OFF_YQ, *vm=ws+OFF_VM, *stats=ws+OFF_ST;
  int *i1=(int*)(ws+OFF_I1), *i2=(int*)(ws+OFF_I2), *i3=(int*)(ws+OFF_I3),
      *knn=(int*)(ws+OFF_KNN);

  const int OCs[6]  = {256, 2048, 8192, 16384, 32768, 65536};
  const int OCoff[6]= {0,   256,  2304, 10496, 26880, 59648};

  struct St { int C,O,Nk,Nq; const float* feat; const float* cq; const float* ck;
              const int* qmap; float* outf; };
  const St st[6] = {
    {8,   32, 4096, 4096, f0, c0, c0, nullptr, f1},   // layer 1
    {32,  64, 4096, 2048, f1, c1, c0, i1,      f2},   // layer 2
    {64, 128, 2048,  512, f2, c2, c1, i2,      f4},   // layer 4
    {128,128,  512,  512, f4, c2, c2, nullptr, f5},   // layer 5
    {128,256,  512,  128, f5, c3, c2, i3,      f6},   // layer 6
    {256,256,  128,  128, f6, c3, c3, nullptr, out + 8*128*3}, // layer 7 -> d_out
  };

  k_feat0 <<<(8*4096+255)/256, 256, 0, stream>>>(x, w_in, b_in, c0, f0, stats);

  WtParams wp;
  for (int s=0;s<6;s++){
    wp.W[s]=Wm[s];
    wp.wl[s]=ws+OFF_WL+OCoff[s];
    wp.wq[s]=ws+OFF_WQ+OCoff[s];
    wp.O[s]=st[s].O; wp.C[s]=st[s].C; wp.OC[s]=OCs[s];
  }
  k_wt_all<<<dim3(256,6), 256, 0, stream>>>(wp);

  // FPS (8) + layer-1 KNN (8192) + layer-1 GEMM (512) in one dispatch
  k_fps_knn1<<<8 + 8*1024 + 512, 256, 0, stream>>>(
      c0, i1, i2, i3, c1, c2, c3, out, knn,
      f0, ws+OFF_WL+OCoff[0], ws+OFF_WQ+OCoff[0], yk, yq);

  for (int s=0;s<6;s++){
    const St& S = st[s];
    dim3 gs(64, B);
    k_gather<<<gs, 256, 0, stream>>>(yk, yq, knn, S.qmap, S.Nq, S.Nk, S.O,
                                     vm, stats + s*64);
    float invcnt = 1.0f / ((float)(S.O/4) * (float)S.Nq * 16.0f);
    int nb = (S.Nq*S.O + 255)/256;
    if (s < 5){
      const St& N = st[s+1];
      int gknn = (N.Nq + 3)/4;
      k_norm_knn<<<dim3(nb + gknn, B), 256, 0, stream>>>(
          vm, stats + s*64, Gm[s], Bm[s], S.Nq, S.O, invcnt, S.outf,
          nb, N.cq, N.Nq, N.ck, N.Nk, knn);
      int rowsPB = 2048 / N.O;
      dim3 gg(N.Nk / rowsPB, B);
      size_t shb = (size_t)rowsPB * (N.C+1) * sizeof(float);
      k_gemm_dual<<<gg, 256, shb, stream>>>(N.feat, N.Nk, N.C, N.O,
                                            ws+OFF_WL+OCoff[s+1],
                                            ws+OFF_WQ+OCoff[s+1], yk, yq);
    } else {
      k_norm<<<dim3(nb, B), 256, 0, stream>>>(vm, stats + s*64, Gm[s], Bm[s],
                                              S.Nq, S.O, invcnt, S.outf);
    }
  }
}